// Round 4
// baseline (344.984 us; speedup 1.0000x reference)
//
#include <hip/hip_runtime.h>

// Pure permutation kernel for KernelActivation (k=2), LDS-staged version,
// now with async global->LDS (global_load_lds width=16, no VGPR round-trip).
//
// Mapping: out_flat[ (((b*32+i)*112 + j)*224 + w)*4 + p*2 + q ] = x[b, 2i+p, 2j+q, w]
//
// One block per (b, i, j0) tile, TJ=8 j-values:
//  - Load phase: two contiguous 14 KB input chunks (16 h-rows x 224 w for
//    c=2i, 2i+1) DMA'd straight into LDS via global_load_lds dwordx4.
//    LDS dest is wave-uniform base + lane*16 (linear in tid) as required.
//  - Store phase: each thread gathers 4 scalars from LDS (<=2-way bank
//    aliasing = free) and writes one contiguous nontemporal float4.

typedef float float4n __attribute__((ext_vector_type(4)));

constexpr int Wd = 224;
constexpr int Hd = 224;
constexpr int Cd = 64;
constexpr int HALF_H = Hd / 2;            // 112
constexpr int HALF_C = Cd / 2;            // 32
constexpr int TJ = 8;                     // j-values per block
constexpr int ROWS = 2 * TJ;              // 16 input h-rows per channel chunk
constexpr int CHUNK_F4 = ROWS * Wd / 4;   // 896 float4 per channel chunk
constexpr int TILE_F4 = 2 * CHUNK_F4;     // 1792 float4 staged / emitted
constexpr int BLOCK = 256;

__global__ __launch_bounds__(BLOCK)
void permute_kernel(const float* __restrict__ x, float4n* __restrict__ out) {
    __shared__ float4n lds4[TILE_F4];     // 28 KB
    float* lds = reinterpret_cast<float*>(lds4);

    const int tile = blockIdx.x;
    const int jb = tile % (HALF_H / TJ);  // 0..13
    const int u  = tile / (HALF_H / TJ);
    const int i  = u % HALF_C;
    const int b  = u / HALF_C;
    const int j0 = jb * TJ;

    const float4n* __restrict__ src0 =
        reinterpret_cast<const float4n*>(x + (((size_t)(b * Cd + 2 * i)     * Hd + 2 * j0) * Wd));
    const float4n* __restrict__ src1 =
        reinterpret_cast<const float4n*>(x + (((size_t)(b * Cd + 2 * i + 1) * Hd + 2 * j0) * Wd));

    const int tid = threadIdx.x;

    // ---- Load phase: async global -> LDS, 16 B per lane, no VGPR round-trip.
    // Iteration k covers t = tid + 256k.  CHUNK_F4 = 896 = 3.5*256; the
    // src0/src1 boundary falls at a multiple of 64, so the select is
    // wave-uniform.  LDS dest: wave-uniform base (tid & ~63) + lane*16.
    #pragma unroll
    for (int k = 0; k < TILE_F4 / BLOCK; ++k) {
        const int t = tid + k * BLOCK;
        const float4n* __restrict__ g =
            (t < CHUNK_F4) ? (src0 + t) : (src1 + (t - CHUNK_F4));
        __builtin_amdgcn_global_load_lds(
            (const __attribute__((address_space(1))) void*)g,
            (__attribute__((address_space(3))) void*)&lds4[k * BLOCK + (tid & ~63)],
            16, 0, 0);
    }
    __syncthreads();   // compiler emits s_waitcnt vmcnt(0) before s_barrier

    // ---- Store phase: LDS gather -> contiguous nontemporal float4 output.
    float4n* __restrict__ dst = out + ((size_t)(b * HALF_C + i) * HALF_H + j0) * Wd;

    #pragma unroll
    for (int t = tid; t < TILE_F4; t += BLOCK) {
        const int jl = t / Wd;            // 0..TJ-1
        const int w  = t % Wd;
        float4n v;
        v.x = lds[(2 * jl    ) * Wd + w];           // c=2i,   h=2j
        v.y = lds[(2 * jl + 1) * Wd + w];           // c=2i,   h=2j+1
        v.z = lds[(ROWS + 2 * jl    ) * Wd + w];    // c=2i+1, h=2j
        v.w = lds[(ROWS + 2 * jl + 1) * Wd + w];    // c=2i+1, h=2j+1
        __builtin_nontemporal_store(v, &dst[t]);
    }
}

extern "C" void kernel_launch(void* const* d_in, const int* in_sizes, int n_in,
                              void* d_out, int out_size, void* d_ws, size_t ws_size,
                              hipStream_t stream) {
    const float* x = (const float*)d_in[0];
    float4n* out = (float4n*)d_out;

    const int Bn = out_size / (Cd * Hd * Wd);          // 16
    const int grid = Bn * HALF_C * (HALF_H / TJ);      // 16*32*14 = 7168

    permute_kernel<<<grid, BLOCK, 0, stream>>>(x, out);
}

// Round 5
// 324.403 us; speedup vs baseline: 1.0634x; 1.0634x over previous
//
#include <hip/hip_runtime.h>

// Pure permutation kernel for KernelActivation (k=2), LDS-staged version.
// REVERT of the global_load_lds experiment: the LDS-DMA path was 1.6x slower
// here (123 us vs ~75 us) because its single vmcnt(0) drain before the barrier
// exposes full HBM latency with no VGPR destinations to partially wait on.
// This version (global->VGPR->LDS with staged waits) measured 325.79 us
// headline (kernel ~70-77 us, ~5.5-5.9 TB/s effective — near the ~6.6 TB/s
// the harness's own fills achieve).
//
// Mapping: out_flat[ (((b*32+i)*112 + j)*224 + w)*4 + p*2 + q ] = x[b, 2i+p, 2j+q, w]
//
// One block per (b, i, j0) tile, TJ=8:
//  - Load phase: two contiguous 14 KB chunks (16 h-rows x 224 w for c=2i,2i+1)
//    staged to LDS via nontemporal float4 loads (16 B/lane, coalesced).
//  - Store phase: 4-scalar LDS gather (<=2-way bank aliasing = free) ->
//    contiguous nontemporal float4 store.

typedef float float4n __attribute__((ext_vector_type(4)));

constexpr int Wd = 224;
constexpr int Hd = 224;
constexpr int Cd = 64;
constexpr int HALF_H = Hd / 2;            // 112
constexpr int HALF_C = Cd / 2;            // 32
constexpr int TJ = 8;                     // j-values per block
constexpr int ROWS = 2 * TJ;              // 16 input h-rows per channel chunk
constexpr int CHUNK_F4 = ROWS * Wd / 4;   // 896 float4 per channel chunk
constexpr int TILE_F4 = 2 * CHUNK_F4;     // 1792 float4 staged / emitted
constexpr int BLOCK = 256;

__global__ __launch_bounds__(BLOCK)
void permute_kernel(const float* __restrict__ x, float4n* __restrict__ out) {
    __shared__ float4n lds4[TILE_F4];     // 28 KB
    float* lds = reinterpret_cast<float*>(lds4);

    const int tile = blockIdx.x;
    const int jb = tile % (HALF_H / TJ);  // 0..13
    const int u  = tile / (HALF_H / TJ);
    const int i  = u % HALF_C;
    const int b  = u / HALF_C;
    const int j0 = jb * TJ;

    const float4n* __restrict__ src0 =
        reinterpret_cast<const float4n*>(x + (((size_t)(b * Cd + 2 * i)     * Hd + 2 * j0) * Wd));
    const float4n* __restrict__ src1 =
        reinterpret_cast<const float4n*>(x + (((size_t)(b * Cd + 2 * i + 1) * Hd + 2 * j0) * Wd));

    const int tid = threadIdx.x;

    // ---- Load phase: global -> VGPR -> LDS, float4, fully coalesced.
    // CHUNK_F4 = 896 is a multiple of 64, so the select is wave-uniform.
    #pragma unroll
    for (int t = tid; t < TILE_F4; t += BLOCK) {
        const float4n* __restrict__ s = (t < CHUNK_F4) ? src0 : src1;
        const int r = (t < CHUNK_F4) ? t : (t - CHUNK_F4);
        lds4[t] = __builtin_nontemporal_load(&s[r]);
    }
    __syncthreads();

    // ---- Store phase: LDS gather -> contiguous nontemporal float4 output.
    float4n* __restrict__ dst = out + ((size_t)(b * HALF_C + i) * HALF_H + j0) * Wd;

    #pragma unroll
    for (int t = tid; t < TILE_F4; t += BLOCK) {
        const int jl = t / Wd;            // 0..TJ-1
        const int w  = t % Wd;
        float4n v;
        v.x = lds[(2 * jl    ) * Wd + w];           // c=2i,   h=2j
        v.y = lds[(2 * jl + 1) * Wd + w];           // c=2i,   h=2j+1
        v.z = lds[(ROWS + 2 * jl    ) * Wd + w];    // c=2i+1, h=2j
        v.w = lds[(ROWS + 2 * jl + 1) * Wd + w];    // c=2i+1, h=2j+1
        __builtin_nontemporal_store(v, &dst[t]);
    }
}

extern "C" void kernel_launch(void* const* d_in, const int* in_sizes, int n_in,
                              void* d_out, int out_size, void* d_ws, size_t ws_size,
                              hipStream_t stream) {
    const float* x = (const float*)d_in[0];
    float4n* out = (float4n*)d_out;

    const int Bn = out_size / (Cd * Hd * Wd);          // 16
    const int grid = Bn * HALF_C * (HALF_H / TJ);      // 16*32*14 = 7168

    permute_kernel<<<grid, BLOCK, 0, stream>>>(x, out);
}